// Round 7
// baseline (184.629 us; speedup 1.0000x reference)
//
#include <hip/hip_runtime.h>

#define Dm  128
#define K1  64
#define TE3 256   // edges per block (main kernel): 4 waves x 64 edges

typedef _Float16 h2 __attribute__((ext_vector_type(2)));

__device__ __forceinline__ float ssp(float x) {
    return __logf(1.0f + __expf(x)) - 0.69314718056f;
}

__device__ __forceinline__ unsigned int pack_h2(_Float16 a, _Float16 b) {
    h2 v = {a, b};
    unsigned int u;
    __builtin_memcpy(&u, &v, 4);
    return u;
}

// Fused prep: blocks [0,T) build the nearest-neighbor filter LUT (midpoint
// sampled, f16 per channel, 256B/row); [T,T+ZB) zero d_out; [T+ZB,..+CB)
// convert atom_features f32 -> f16. 128 threads/block.
__global__ void prep_all(const float* __restrict__ centers,
                         const float* __restrict__ gamma,
                         const float* __restrict__ W1,
                         const float* __restrict__ b1,
                         const float* __restrict__ W2,
                         const float* __restrict__ b2,
                         const float* __restrict__ af,
                         unsigned short* __restrict__ tab,
                         _Float16* __restrict__ afh,
                         float* __restrict__ out,
                         int T, int ZB, int CB, int NATD) {
    __shared__ float rbf[K1];
    __shared__ float h1s[Dm];
    const int blk = blockIdx.x;
    const int t = threadIdx.x;          // 0..127

    if (blk < T) {
        const int j = blk;
        const float d = ((float)j + 0.5f) / (float)T;   // midpoint sample
        if (t < K1) {
            float diff = d - centers[t];
            rbf[t] = __expf(-gamma[t] * diff * diff);
        }
        __syncthreads();
        float a1 = b1[t];
        #pragma unroll 4
        for (int k = 0; k < K1; ++k) a1 = fmaf(rbf[k], W1[k * Dm + t], a1);
        h1s[t] = ssp(a1);
        __syncthreads();
        float a2 = b2[t];
        #pragma unroll 4
        for (int k = 0; k < Dm; ++k) a2 = fmaf(h1s[k], W2[k * Dm + t], a2);
        float F = ssp(a2);
        _Float16 fh = (_Float16)F;
        unsigned short us;
        __builtin_memcpy(&us, &fh, 2);
        tab[(size_t)j * Dm + t] = us;
    } else if (blk < T + ZB) {
        const int b = blk - T;
        float4* o4 = (float4*)out;
        const int n4 = NATD >> 2;
        const float4 z = make_float4(0.f, 0.f, 0.f, 0.f);
        for (int i = b * 128 + t; i < n4; i += ZB * 128) o4[i] = z;
    } else if (CB > 0) {
        const int b = blk - T - ZB;
        const float4* a4 = (const float4*)af;
        uint2* d4 = (uint2*)afh;
        const int n4 = NATD >> 2;
        for (int i = b * 128 + t; i < n4; i += CB * 128) {
            float4 v = a4[i];
            uint2 st;
            st.x = pack_h2((_Float16)v.x, (_Float16)v.y);
            st.y = pack_h2((_Float16)v.z, (_Float16)v.w);
            d4[i] = st;
        }
    }
}

template<bool AF16>
__global__ __launch_bounds__(256, 8) void cfconv_lut3(
    const float* __restrict__ af,
    const _Float16* __restrict__ afh,
    const float* __restrict__ distances,
    const int*   __restrict__ idx_j,
    const int*   __restrict__ seg_i,
    const unsigned short* __restrict__ tab,
    float* __restrict__ out, int T)
{
    __shared__ int4 meta[TE3];   // {idx_j, seg_i, lut row, pad}
    const int t = threadIdx.x;
    const long eb = (long)blockIdx.x * TE3;

    {
        float d = distances[eb + t];
        int iv = (int)(d * (float)T);
        iv = iv < 0 ? 0 : (iv > T - 1 ? T - 1 : iv);
        meta[t] = make_int4(idx_j[eb + t], seg_i[eb + t], iv, 0);
    }
    __syncthreads();

    const int p  = t & 63;      // channel pair -> channels {2p, 2p+1}
    const int g  = t >> 6;      // wave id = 64-edge group
    const int m0 = g * 64;

    int   cur = __builtin_amdgcn_readfirstlane(meta[m0].y);
    float s0 = 0.f, s1 = 0.f;

    #pragma unroll
    for (int b = 0; b < 4; ++b) {
        const int mb = m0 + b * 16;
        h2  tb[16], av[16];
        int sg[16];
        // issue all 32 loads before consuming — deep in-flight queue
        #pragma unroll
        for (int j = 0; j < 16; ++j) {
            int4 md = meta[mb + j];
            int id = __builtin_amdgcn_readfirstlane(md.x);   // scalar -> saddr
            sg[j]  = __builtin_amdgcn_readfirstlane(md.y);
            int iv = __builtin_amdgcn_readfirstlane(md.z);
            tb[j] = *(const h2*)&tab[(size_t)iv * Dm + p * 2];
            if (AF16) {
                av[j] = *(const h2*)&afh[(size_t)id * Dm + p * 2];
            } else {
                float2 aa = *(const float2*)&af[(size_t)id * Dm + p * 2];
                av[j][0] = (_Float16)aa.x;
                av[j][1] = (_Float16)aa.y;
            }
        }
        #pragma unroll
        for (int j = 0; j < 16; ++j) {
            h2 pr = tb[j] * av[j];          // v_pk_mul_f16
            float q0 = (float)pr[0];
            float q1 = (float)pr[1];
            if (sg[j] != cur) {             // wave-uniform branch (sg scalar)
                float* op = &out[(size_t)cur * Dm + p * 2];
                atomicAdd(op,     s0);
                atomicAdd(op + 1, s1);
                cur = sg[j];
                s0 = q0; s1 = q1;
            } else {
                s0 += q0; s1 += q1;
            }
        }
    }
    float* op = &out[(size_t)cur * Dm + p * 2];
    atomicAdd(op,     s0);
    atomicAdd(op + 1, s1);
}

extern "C" void kernel_launch(void* const* d_in, const int* in_sizes, int n_in,
                              void* d_out, int out_size, void* d_ws, size_t ws_size,
                              hipStream_t stream) {
    const float* atom_features = (const float*)d_in[0];
    const float* distances     = (const float*)d_in[1];
    const int*   idx_j         = (const int*)d_in[2];
    const int*   seg_i         = (const int*)d_in[3];
    const float* centers       = (const float*)d_in[4];
    const float* gamma         = (const float*)d_in[5];
    const float* W1            = (const float*)d_in[6];
    const float* b1            = (const float*)d_in[7];
    const float* W2            = (const float*)d_in[8];
    const float* b2            = (const float*)d_in[9];

    const int E    = in_sizes[1];   // 800000, divisible by TE3=256
    const int NATD = out_size;      // 50000*128
    float* out = (float*)d_out;

    // ws: [tab: T*Dm*2 bytes][afh: NATD*2 bytes]
    int T; bool af16;
    const size_t afh_bytes = (size_t)NATD * 2;
    if      (ws_size >= (size_t)8192 * Dm * 2 + afh_bytes) { T = 8192; af16 = true;  }
    else if (ws_size >= (size_t)8192 * Dm * 2)             { T = 8192; af16 = false; }
    else                                                   { T = 1024; af16 = false; }

    unsigned short* tab = (unsigned short*)d_ws;
    _Float16*       afh = (_Float16*)((char*)d_ws + (size_t)T * Dm * 2);

    const int ZB = 512;
    const int CB = af16 ? 512 : 0;
    prep_all<<<T + ZB + CB, 128, 0, stream>>>(
        centers, gamma, W1, b1, W2, b2, atom_features,
        tab, afh, out, T, ZB, CB, NATD);

    if (af16)
        cfconv_lut3<true><<<E / TE3, 256, 0, stream>>>(
            atom_features, afh, distances, idx_j, seg_i, tab, out, T);
    else
        cfconv_lut3<false><<<E / TE3, 256, 0, stream>>>(
            atom_features, afh, distances, idx_j, seg_i, tab, out, T);
}

// Round 8
// 169.559 us; speedup vs baseline: 1.0889x; 1.0889x over previous
//
#include <hip/hip_runtime.h>

#define Dm  128
#define K1  64
#define TE3 256   // edges per block (main kernel): 4 waves x 64 edges
#define LUT_ROWS 32

typedef _Float16 h2 __attribute__((ext_vector_type(2)));

__device__ __forceinline__ float ssp(float x) {
    return __logf(1.0f + __expf(x)) - 0.69314718056f;
}

__device__ __forceinline__ unsigned int pack_h2(_Float16 a, _Float16 b) {
    h2 v = {a, b};
    unsigned int u;
    __builtin_memcpy(&u, &v, 4);
    return u;
}

// Fused prep, 256 threads/block, grid partitioned three ways:
//   [0, LUTB):           build NN filter LUT, 32 rows/block, weights amortized 16x
//   [LUTB, LUTB+ZB):     zero d_out
//   [LUTB+ZB, ..+CB):    convert atom_features f32 -> f16
__global__ void prep_all(const float* __restrict__ centers,
                         const float* __restrict__ gamma,
                         const float* __restrict__ W1,
                         const float* __restrict__ b1,
                         const float* __restrict__ W2,
                         const float* __restrict__ b2,
                         const float* __restrict__ af,
                         unsigned short* __restrict__ tab,
                         _Float16* __restrict__ afh,
                         float* __restrict__ out,
                         int T, int LUTB, int ZB, int CB, int NATD) {
    __shared__ float rbf[LUT_ROWS][K1];    // 8 KB
    __shared__ float h1s[LUT_ROWS][Dm];    // 16 KB
    const int blk = blockIdx.x;
    const int t = threadIdx.x;             // 0..255

    if (blk < LUTB) {
        const int r0 = blk * LUT_ROWS;
        const float invT = 1.0f / (float)T;
        for (int i = t; i < LUT_ROWS * K1; i += 256) {
            int r = i >> 6, k = i & 63;
            float d = ((float)(r0 + r) + 0.5f) * invT;   // midpoint sample
            float diff = d - centers[k];
            rbf[r][k] = __expf(-gamma[k] * diff * diff);
        }
        __syncthreads();
        const int ch = t & 127;
        const int rb = (t >> 7) * 16;      // rows [rb, rb+16)
        float acc[16];
        {
            float b = b1[ch];
            #pragma unroll
            for (int r = 0; r < 16; ++r) acc[r] = b;
        }
        for (int k = 0; k < K1; ++k) {
            float w = W1[k * Dm + ch];
            #pragma unroll
            for (int r = 0; r < 16; ++r) acc[r] = fmaf(rbf[rb + r][k], w, acc[r]);
        }
        #pragma unroll
        for (int r = 0; r < 16; ++r) h1s[rb + r][ch] = ssp(acc[r]);
        __syncthreads();
        {
            float b = b2[ch];
            #pragma unroll
            for (int r = 0; r < 16; ++r) acc[r] = b;
        }
        for (int k = 0; k < Dm; ++k) {
            float w = W2[k * Dm + ch];
            #pragma unroll
            for (int r = 0; r < 16; ++r) acc[r] = fmaf(h1s[rb + r][k], w, acc[r]);
        }
        #pragma unroll
        for (int r = 0; r < 16; ++r) {
            _Float16 fh = (_Float16)ssp(acc[r]);
            unsigned short us;
            __builtin_memcpy(&us, &fh, 2);
            tab[(size_t)(r0 + rb + r) * Dm + ch] = us;
        }
    } else if (blk < LUTB + ZB) {
        const int b = blk - LUTB;
        float4* o4 = (float4*)out;
        const int n4 = NATD >> 2;
        const float4 z = make_float4(0.f, 0.f, 0.f, 0.f);
        for (int i = b * 256 + t; i < n4; i += ZB * 256) o4[i] = z;
    } else if (CB > 0) {
        const int b = blk - LUTB - ZB;
        const float4* a4 = (const float4*)af;
        uint2* d4 = (uint2*)afh;
        const int n4 = NATD >> 2;
        for (int i = b * 256 + t; i < n4; i += CB * 256) {
            float4 v = a4[i];
            uint2 st;
            st.x = pack_h2((_Float16)v.x, (_Float16)v.y);
            st.y = pack_h2((_Float16)v.z, (_Float16)v.w);
            d4[i] = st;
        }
    }
}

template<bool AF16>
__global__ __launch_bounds__(256, 5) void cfconv_lut4(
    const float* __restrict__ af,
    const _Float16* __restrict__ afh,
    const float* __restrict__ distances,
    const int*   __restrict__ idx_j,
    const int*   __restrict__ seg_i,
    const unsigned short* __restrict__ tab,
    float* __restrict__ out, int T)
{
    __shared__ int4 meta[TE3];   // {idx_j, seg_i, lut row, pad}
    const int t = threadIdx.x;
    const long eb = (long)blockIdx.x * TE3;

    {
        float d = distances[eb + t];
        int iv = (int)(d * (float)T);
        iv = iv < 0 ? 0 : (iv > T - 1 ? T - 1 : iv);
        meta[t] = make_int4(idx_j[eb + t], seg_i[eb + t], iv, 0);
    }
    __syncthreads();

    const int p  = t & 63;      // channel pair -> channels {2p, 2p+1}
    const int g  = t >> 6;      // wave id = 64-edge group
    const int m0 = g * 64;

    int   cur = __builtin_amdgcn_readfirstlane(meta[m0].y);
    float s0 = 0.f, s1 = 0.f;

    #pragma unroll
    for (int b = 0; b < 2; ++b) {
        const int mb = m0 + b * 32;
        h2  tb[32], av[32];
        int sg[32];
        // issue all 64 loads before consuming — deep in-flight queue
        #pragma unroll
        for (int j = 0; j < 32; ++j) {
            int4 md = meta[mb + j];
            int id = __builtin_amdgcn_readfirstlane(md.x);   // scalar -> saddr
            sg[j]  = __builtin_amdgcn_readfirstlane(md.y);
            int iv = __builtin_amdgcn_readfirstlane(md.z);
            tb[j] = *(const h2*)&tab[(size_t)iv * Dm + p * 2];
            if (AF16) {
                av[j] = *(const h2*)&afh[(size_t)id * Dm + p * 2];
            } else {
                float2 aa = *(const float2*)&af[(size_t)id * Dm + p * 2];
                av[j][0] = (_Float16)aa.x;
                av[j][1] = (_Float16)aa.y;
            }
        }
        #pragma unroll
        for (int j = 0; j < 32; ++j) {
            h2 pr = tb[j] * av[j];          // v_pk_mul_f16
            float q0 = (float)pr[0];
            float q1 = (float)pr[1];
            if (sg[j] != cur) {             // wave-uniform branch (sg scalar)
                float* op = &out[(size_t)cur * Dm + p * 2];
                atomicAdd(op,     s0);
                atomicAdd(op + 1, s1);
                cur = sg[j];
                s0 = q0; s1 = q1;
            } else {
                s0 += q0; s1 += q1;
            }
        }
    }
    float* op = &out[(size_t)cur * Dm + p * 2];
    atomicAdd(op,     s0);
    atomicAdd(op + 1, s1);
}

extern "C" void kernel_launch(void* const* d_in, const int* in_sizes, int n_in,
                              void* d_out, int out_size, void* d_ws, size_t ws_size,
                              hipStream_t stream) {
    const float* atom_features = (const float*)d_in[0];
    const float* distances     = (const float*)d_in[1];
    const int*   idx_j         = (const int*)d_in[2];
    const int*   seg_i         = (const int*)d_in[3];
    const float* centers       = (const float*)d_in[4];
    const float* gamma         = (const float*)d_in[5];
    const float* W1            = (const float*)d_in[6];
    const float* b1            = (const float*)d_in[7];
    const float* W2            = (const float*)d_in[8];
    const float* b2            = (const float*)d_in[9];

    const int E    = in_sizes[1];   // 800000, divisible by TE3=256
    const int NATD = out_size;      // 50000*128
    float* out = (float*)d_out;

    // ws: [tab: T*Dm*2 bytes][afh: NATD*2 bytes]
    int T; bool af16;
    const size_t afh_bytes = (size_t)NATD * 2;
    if      (ws_size >= (size_t)2048 * Dm * 2 + afh_bytes) { T = 2048; af16 = true;  }
    else if (ws_size >= (size_t)2048 * Dm * 2)             { T = 2048; af16 = false; }
    else                                                   { T = 512;  af16 = false; }

    unsigned short* tab = (unsigned short*)d_ws;
    _Float16*       afh = (_Float16*)((char*)d_ws + (size_t)T * Dm * 2);

    const int LUTB = T / LUT_ROWS;      // 64 blocks at T=2048
    const int ZB = 256;
    const int CB = af16 ? 256 : 0;
    prep_all<<<LUTB + ZB + CB, 256, 0, stream>>>(
        centers, gamma, W1, b1, W2, b2, atom_features,
        tab, afh, out, T, LUTB, ZB, CB, NATD);

    if (af16)
        cfconv_lut4<true><<<E / TE3, 256, 0, stream>>>(
            atom_features, afh, distances, idx_j, seg_i, tab, out, T);
    else
        cfconv_lut4<false><<<E / TE3, 256, 0, stream>>>(
            atom_features, afh, distances, idx_j, seg_i, tab, out, T);
}